// Round 13
// baseline (797.254 us; speedup 1.0000x reference)
//
#include <hip/hip_runtime.h>
#include <math.h>

#define N_ENT 30000
#define R_REL 1000
#define T_EDGE 300000
#define B_PAIR 1024
#define NNZ_E 600000
#define GAMMAF 3.0f
#define EPSV 1e-12f
#define EMBD 768
#define NPAD 30720           // N_ENT padded to 240 tiles of 128 (zeroed pad rows in Eh; qn[pad]=1e30)
#define NT128 240            // n-tiles of 128 for gemmB
#define PTILES 480           // lse partial tiles per row (2 per 128-tile)
#define SCB 118              // scan blocks per list (118*256 >= 30000)

typedef _Float16 half8 __attribute__((ext_vector_type(8)));
typedef _Float16 half4v __attribute__((ext_vector_type(4)));
typedef _Float16 half2v __attribute__((ext_vector_type(2)));
typedef float f32x4 __attribute__((ext_vector_type(4)));

__device__ inline void gl_lds16(const _Float16* g, _Float16* l){
  __builtin_amdgcn_global_load_lds(
      (const __attribute__((address_space(1))) unsigned int*)g,
      (__attribute__((address_space(3))) unsigned int*)l, 16, 0, 0);
}

__device__ inline float waveRedSum(float v){
  #pragma unroll
  for(int m=32;m>=1;m>>=1) v += __shfl_xor(v, m, 64);
  return v;
}

__device__ inline float fast_tanh(float x){
  x = fminf(10.f, fmaxf(-10.f, x));
  float e = __expf(2.f*x);
  return (e-1.f)/(e+1.f);
}

// ---- fused prep: fp16 convert embeddings + zero Eh pad rows + relnorm/expdot + edge counts ----
__global__ __launch_bounds__(256) void k_prep(const float* __restrict__ ent, const float* __restrict__ rel,
      const float* __restrict__ ae, const float* __restrict__ ar,
      _Float16* ehE, _Float16* ehR, _Float16* Eh, _Float16* relnH, float* expdot,
      const int* __restrict__ rA, int* cA, const int* __restrict__ rE, int* cE,
      const int* __restrict__ rR, int* cR){
  int i = blockIdx.x*256 + threadIdx.x;
  if(i < N_ENT*128) ehE[i] = (_Float16)ent[i];
  if(i < R_REL*128) ehR[i] = (_Float16)rel[i];
  if(i < (NPAD-N_ENT)*EMBD) Eh[(size_t)N_ENT*EMBD + i] = (_Float16)0.f;
  if(i < T_EDGE) atomicAdd(&cA[rA[i]], 1);
  if(i < NNZ_E){ atomicAdd(&cE[rE[i]], 1); atomicAdd(&cR[rR[i]], 1); }
  int r = i >> 6;
  if(r < R_REL){
    int lane = i & 63;
    float2 v = *(const float2*)(rel + (size_t)r*128 + lane*2);
    float ss = waveRedSum(v.x*v.x + v.y*v.y);
    float nrm = fmaxf(sqrtf(ss), EPSV);
    float2 u; u.x = v.x/nrm; u.y = v.y/nrm;
    half2v uh = {(_Float16)u.x, (_Float16)u.y};
    *(half2v*)(relnH + (size_t)r*128 + lane*2) = uh;
    const float* ks[4] = {ae, ae+128, ar, ar+128};   // ent l0, ent l1, rel l0, rel l1
    #pragma unroll
    for(int k=0;k<4;k++){
      float2 w = *(const float2*)(ks[k] + lane*2);
      float d = waveRedSum(u.x*w.x + u.y*w.y);
      if(lane==0) expdot[k*R_REL + r] = __expf(d);
    }
  }
}

// ---- scan phase A: per-block exclusive scan + block totals; grid (SCB, 3) ----
__global__ __launch_bounds__(256) void k_scanA(const int* c0, const int* c1, const int* c2,
                                               int* s0, int* s1, int* s2, int* part){
  const int* cnt = blockIdx.y==0 ? c0 : (blockIdx.y==1 ? c1 : c2);
  int* start     = blockIdx.y==0 ? s0 : (blockIdx.y==1 ? s1 : s2);
  __shared__ int wsum[4];
  int i = blockIdx.x*256 + threadIdx.x;
  int lane = threadIdx.x & 63, wid = threadIdx.x >> 6;
  int v = (i < N_ENT) ? cnt[i] : 0;
  int x = v;
  #pragma unroll
  for(int off=1; off<64; off<<=1){ int t=__shfl_up(x,off,64); if(lane>=off) x+=t; }
  if(lane==63) wsum[wid] = x;
  __syncthreads();
  int woff = 0;
  #pragma unroll
  for(int k=0;k<3;k++) if(k < wid) woff += wsum[k];
  if(i < N_ENT) start[i] = woff + x - v;
  if(threadIdx.x == 255) part[blockIdx.y*SCB + blockIdx.x] = woff + x;
}

// ---- scan phase B: 1 block; wave per list scans SCB partials ----
__global__ __launch_bounds__(256) void k_scanB(int* part, int* tots){
  int wid = threadIdx.x>>6, lane = threadIdx.x&63;
  if(wid >= 3) return;
  int base = wid*SCB;
  int v0 = part[base + lane];
  int i1 = 64 + lane;
  int v1 = (i1 < SCB) ? part[base + i1] : 0;
  int x0 = v0, x1 = v1;
  #pragma unroll
  for(int off=1; off<64; off<<=1){
    int t0=__shfl_up(x0,off,64), t1=__shfl_up(x1,off,64);
    if(lane>=off){ x0+=t0; x1+=t1; }
  }
  int t0 = __shfl(x0, 63, 64);
  int t1 = __shfl(x1, 63, 64);
  part[base + lane] = x0 - v0;
  if(i1 < SCB) part[base + i1] = t0 + x1 - v1;
  if(lane == 0) tots[wid] = t0 + t1;
}

// ---- scan phase C: add block offsets, write cursor + totals ----
__global__ __launch_bounds__(256) void k_scanC(int* s0, int* s1, int* s2,
                                               int* u0, int* u1, int* u2,
                                               const int* part, const int* tots){
  int y = blockIdx.y;
  int* start  = y==0 ? s0 : (y==1 ? s1 : s2);
  int* cursor = y==0 ? u0 : (y==1 ? u1 : u2);
  int i = blockIdx.x*256 + threadIdx.x;
  int off = part[y*SCB + blockIdx.x];
  if(i < N_ENT){ int v = start[i] + off; start[i] = v; cursor[i] = v; }
  if(i == 0) start[N_ENT] = tots[y];
}

// ---- scatter all three edge lists into CSR order, one launch ----
//      A-list col+rid packed into ONE int2 (8B) store: r12 PMC showed k_scatter3 is
//      write-amplification-bound (WRITE_SIZE 108MB for ~7MB payload, VALUBusy 0.3% --
//      every random 4B store dirties a full 64B line). Merging the two 4B stores at the
//      same index p into one 8B store cuts dirtied lines 1.8M -> 1.5M.
__global__ __launch_bounds__(256) void k_scatter3(
      const int* __restrict__ rA, const int* __restrict__ cAj, const int* __restrict__ rid,
      int* uA, int2* sAB,
      const int* __restrict__ rE, const int* __restrict__ cEj, int* uE, int* scolE,
      const int* __restrict__ rR, const int* __restrict__ cRj, int* uR, int* scolR){
  int e = blockIdx.x*256 + threadIdx.x;
  if(e < T_EDGE){
    int p = atomicAdd(&uA[rA[e]], 1);
    sAB[p] = make_int2(cAj[e], rid[e]);
  }
  if(e < NNZ_E){
    int p = atomicAdd(&uE[rE[e]], 1);
    scolE[p] = cEj[e];
    int q = atomicAdd(&uR[rR[e]], 1);
    scolR[q] = cRj[e];
  }
}

// ---- _avg via CSR gather from fp16 src (ent: y=0, rel: y=1), fused tanh ----
//      2-edge unroll is the measured optimum: r10's 4-edge unroll regressed total 780->822
//      (mean degree ~10-20 -> bigger scalar tail + register pressure). Keep 2-wide.
__global__ __launch_bounds__(256) void k_avg2(const int* __restrict__ startE, const int* __restrict__ scolE,
                        const _Float16* __restrict__ srcE,
                        const int* __restrict__ startR, const int* __restrict__ scolR,
                        const _Float16* __restrict__ srcR,
                        _Float16* featC, _Float16* Eh){
  int which = blockIdx.y;
  const int* start = which? startR : startE;
  const int* scol  = which? scolR : scolE;
  const _Float16* src = which? srcR : srcE;
  int pairOff = which? 2 : 0;
  int coloff  = which? 384 : 0;
  int r = blockIdx.x*4 + (threadIdx.x>>6);
  int lane = threadIdx.x & 63;
  int s0 = start[r], s1 = start[r+1];
  float ax=0.f, ay=0.f;
  int e = s0;
  for(; e+1<s1; e+=2){
    int c0 = scol[e], c1 = scol[e+1];
    half2v v0 = *(const half2v*)(src + (size_t)c0*128 + lane*2);
    half2v v1 = *(const half2v*)(src + (size_t)c1*128 + lane*2);
    ax += (float)v0[0] + (float)v1[0]; ay += (float)v0[1] + (float)v1[1];
  }
  if(e<s1){
    int c0 = scol[e];
    half2v v0 = *(const half2v*)(src + (size_t)c0*128 + lane*2);
    ax += (float)v0[0]; ay += (float)v0[1];
  }
  float inv = (s1>s0) ? 1.0f/(float)(s1-s0) : 0.f;
  float vx = fast_tanh(ax*inv), vy = fast_tanh(ay*inv);
  half2v hv = {(_Float16)vx, (_Float16)vy};
  *(half2v*)(featC + (size_t)r*256 + lane*4 + pairOff) = hv;
  *(half2v*)(Eh + (size_t)r*EMBD + coloff + lane*2) = hv;
}

// ---- fused dual-stack GAT layer: one pass does ent+rel Householder+softmax ----
//      2-edge unroll is the measured optimum (r10 4-wide regressed +42us).
//      A-list indices read as packed int2 (col, rid) -- see k_scatter3 note.
__global__ __launch_bounds__(256) void k_edge2(const int* __restrict__ start, const int2* __restrict__ sAB,
      const _Float16* __restrict__ relnH,
      const float* __restrict__ expE, const float* __restrict__ expR,
      const _Float16* __restrict__ featIn, _Float16* featOut, _Float16* Eh, int colEnt, int colRel){
  int r = blockIdx.x*4 + (threadIdx.x>>6);
  int lane = threadIdx.x & 63;
  int s0 = start[r], s1 = start[r+1];
  float aEx=0,aEy=0,aRx=0,aRy=0, swE=0, swR=0;
  int e = s0;
  for(; e+1<s1; e+=2){
    int2 i0 = sAB[e], i1 = sAB[e+1];
    int c0=i0.x, q0=i0.y, c1=i1.x, q1=i1.y;
    float wE0=expE[q0], wR0=expR[q0], wE1=expE[q1], wR1=expR[q1];
    half2v u0h = *(const half2v*)(relnH + (size_t)q0*128 + lane*2);
    half2v u1h = *(const half2v*)(relnH + (size_t)q1*128 + lane*2);
    half4v h0 = *(const half4v*)(featIn + (size_t)c0*256 + lane*4);
    half4v h1 = *(const half4v*)(featIn + (size_t)c1*256 + lane*4);
    float u0x=(float)u0h[0], u0y=(float)u0h[1], u1x=(float)u1h[0], u1y=(float)u1h[1];
    float e0x=(float)h0[0], e0y=(float)h0[1], r0x=(float)h0[2], r0y=(float)h0[3];
    float e1x=(float)h1[0], e1y=(float)h1[1], r1x=(float)h1[2], r1y=(float)h1[3];
    float d0 = e0x*u0x + e0y*u0y;
    float d1 = r0x*u0x + r0y*u0y;
    float d2 = e1x*u1x + e1y*u1y;
    float d3 = r1x*u1x + r1y*u1y;
    #pragma unroll
    for(int m=32;m>=1;m>>=1){
      d0 += __shfl_xor(d0,m,64); d1 += __shfl_xor(d1,m,64);
      d2 += __shfl_xor(d2,m,64); d3 += __shfl_xor(d3,m,64);
    }
    aEx += wE0*(e0x - 2.f*d0*u0x) + wE1*(e1x - 2.f*d2*u1x);
    aEy += wE0*(e0y - 2.f*d0*u0y) + wE1*(e1y - 2.f*d2*u1y);
    aRx += wR0*(r0x - 2.f*d1*u0x) + wR1*(r1x - 2.f*d3*u1x);
    aRy += wR0*(r0y - 2.f*d1*u0y) + wR1*(r1y - 2.f*d3*u1y);
    swE += wE0+wE1; swR += wR0+wR1;
  }
  if(e<s1){
    int2 i0 = sAB[e];
    int c0=i0.x, q0=i0.y;
    float wE0=expE[q0], wR0=expR[q0];
    half2v u0h = *(const half2v*)(relnH + (size_t)q0*128 + lane*2);
    half4v h0 = *(const half4v*)(featIn + (size_t)c0*256 + lane*4);
    float u0x=(float)u0h[0], u0y=(float)u0h[1];
    float e0x=(float)h0[0], e0y=(float)h0[1], r0x=(float)h0[2], r0y=(float)h0[3];
    float d0 = e0x*u0x + e0y*u0y;
    float d1 = r0x*u0x + r0y*u0y;
    #pragma unroll
    for(int m=32;m>=1;m>>=1){ d0 += __shfl_xor(d0,m,64); d1 += __shfl_xor(d1,m,64); }
    aEx += wE0*(e0x - 2.f*d0*u0x);
    aEy += wE0*(e0y - 2.f*d0*u0y);
    aRx += wR0*(r0x - 2.f*d1*u0x);
    aRy += wR0*(r0y - 2.f*d1*u0y);
    swE += wE0; swR += wR0;
  }
  float iE = (s1>s0) ? 1.f/swE : 0.f;
  float iR = (s1>s0) ? 1.f/swR : 0.f;
  float vEx = fast_tanh(aEx*iE), vEy = fast_tanh(aEy*iE);
  float vRx = fast_tanh(aRx*iR), vRy = fast_tanh(aRy*iR);
  half4v ov = {(_Float16)vEx,(_Float16)vEy,(_Float16)vRx,(_Float16)vRy};
  *(half4v*)(featOut + (size_t)r*256 + lane*4) = ov;
  half2v he = {(_Float16)vEx,(_Float16)vEy};
  half2v hr = {(_Float16)vRx,(_Float16)vRy};
  *(half2v*)(Eh + (size_t)r*EMBD + colEnt + lane*2) = he;
  *(half2v*)(Eh + (size_t)r*EMBD + colRel + lane*2) = hr;
}

// ---- fused post-GAT pass: transp (b<5760) | gather (b<6784) | qnstats (b<7024) ----
__global__ __launch_bounds__(256) void k_post(const _Float16* __restrict__ Eh, _Float16* embT,
      const int* __restrict__ tp, _Float16* Wh, float* cvec,
      float* qn, float* Svec, float* Pvec, float* QQ){
  __shared__ __align__(16) _Float16 til[64][72];
  __shared__ float sh0[256], sh1[256], sh2[256];
  int b = blockIdx.x;
  int tid = threadIdx.x;
  if(b < 5760){
    // ---- transpose Eh -> embT (768 x NPAD) ----
    int r0 = (b % 480)*64, c0 = (b / 480)*64;
    int rr = tid>>3, c8 = (tid&7)*8;
    #pragma unroll
    for(int p=0;p<2;p++){
      int gr = r0 + rr + p*32;
      uint4 v = make_uint4(0u,0u,0u,0u);
      if(gr < N_ENT) v = *(const uint4*)(Eh + (size_t)gr*EMBD + c0 + c8);
      *(uint4*)&til[rr + p*32][c8] = v;
    }
    __syncthreads();
    #pragma unroll
    for(int p=0;p<2;p++){
      int cc = rr + p*32;
      __align__(16) _Float16 tmp[8];
      #pragma unroll
      for(int j=0;j<8;j++) tmp[j] = til[c8 + j][cc];
      *(uint4*)(embT + (size_t)(c0+cc)*NPAD + r0 + c8) = *(uint4*)tmp;
    }
  } else if(b < 5760 + B_PAIR){
    // ---- gather pair rows -> Wh, cvec ----
    int i = b - 5760;
    int l = tp[2*i], r = tp[2*i+1];
    float sl=0.f, sr=0.f, sp=0.f;
    for(int c=tid;c<EMBD;c+=256){
      _Float16 lh = Eh[(size_t)l*EMBD+c], rh = Eh[(size_t)r*EMBD+c];
      float le = (float)lh, re = (float)rh;
      Wh[(size_t)i*EMBD+c]=lh; Wh[(size_t)(B_PAIR+i)*EMBD+c]=rh;
      sl += le*le; sr += re*re; float d = le-re; sp += d*d;
    }
    sh0[tid]=sl; sh1[tid]=sr; sh2[tid]=sp;
    __syncthreads();
    for(int w=128;w>0;w>>=1){
      if(tid<w){ sh0[tid]+=sh0[tid+w]; sh1[tid]+=sh1[tid+w]; sh2[tid]+=sh2[tid+w]; }
      __syncthreads();
    }
    if(tid==0){
      float pos = sh2[0];
      cvec[i]        = pos + GAMMAF - sh0[0];
      cvec[B_PAIR+i] = pos + GAMMAF - sh1[0];
    }
  } else {
    // ---- qn + embstats: wave per row, strided over 960 waves ----
    int wid = tid>>6, lane = tid&63;
    int gw = (b - 5760 - B_PAIR)*4 + wid;
    float s[12], p[12];
    #pragma unroll
    for(int q=0;q<12;q++){ s[q]=0.f; p[q]=0.f; }
    float q1=0.f, q2=0.f;
    for(int r=gw; r<NPAD; r+=960){
      if(r >= N_ENT){ if(lane==0) qn[r] = 1e30f; continue; }
      float v[12]; float ss=0.f;
      #pragma unroll
      for(int q=0;q<12;q++){ v[q] = (float)Eh[(size_t)r*EMBD + lane + 64*q]; ss += v[q]*v[q]; }
      ss = waveRedSum(ss);
      ss = __shfl(ss, 0, 64);
      if(lane==0){ qn[r] = ss; q1 += ss; q2 += ss*ss; }
      #pragma unroll
      for(int q=0;q<12;q++){ s[q] += v[q]; p[q] += ss*v[q]; }
    }
    #pragma unroll
    for(int q=0;q<12;q++){
      unsafeAtomicAdd(&Svec[lane + 64*q], s[q]);
      unsafeAtomicAdd(&Pvec[lane + 64*q], p[q]);
    }
    if(lane==0){ unsafeAtomicAdd(&QQ[0], q1); unsafeAtomicAdd(&QQ[1], q2); }
  }
}

// ---- G = E^T E via f16 MFMA on embT; 128x128 tiles, split-K 32 with XCD-owned k-slices ----
//      grid 1152: xcd = id&7, rest = id>>3 (0..143); kslice = xcd + 8*(rest/36) in [0,32); tile = rest%36
//      (confirmed win together with k_gemmTh regrid: ~-50us total, r7/r8/r9)
__global__ __launch_bounds__(256) void k_syrk(const _Float16* __restrict__ embT, float* G){
  __shared__ __align__(16) _Float16 As[128*64];
  __shared__ __align__(16) _Float16 Bs[128*64];
  int id = blockIdx.x;
  int xcd = id & 7, rest = id >> 3;
  int kslc = xcd + 8*(rest/36);
  int tile = rest % 36;
  int m0 = (tile/6)*128, n0 = (tile%6)*128;
  int kbeg = kslc*960, kend = kbeg + 960;
  int tid = threadIdx.x;
  int w = tid>>6, lane = tid&63;
  int quad = lane>>4, l15 = lane&15;
  int lr = lane>>3, lc = lane&7;
  int wm = (w>>1)*64, wn = (w&1)*64;
  f32x4 acc[4][4];
  #pragma unroll
  for(int i=0;i<4;i++)
    #pragma unroll
    for(int j=0;j<4;j++) acc[i][j] = (f32x4){0.f,0.f,0.f,0.f};
  for(int k0=kbeg;k0<kend;k0+=64){
    #pragma unroll
    for(int p=0;p<4;p++){
      int r = p*32 + w*8 + lr;
      int cg = lc ^ (r&7);
      gl_lds16(embT + (size_t)(m0+r)*NPAD + k0 + cg*8, As + (p*32 + w*8)*64);
      gl_lds16(embT + (size_t)(n0+r)*NPAD + k0 + cg*8, Bs + (p*32 + w*8)*64);
    }
    __syncthreads();
    #pragma unroll
    for(int ks=0;ks<2;ks++){
      half8 af[4], bf[4];
      #pragma unroll
      for(int i=0;i<4;i++){
        int ml = wm + i*16 + l15;
        af[i] = *(half8*)(As + ml*64 + (((ks<<2)|quad) ^ (ml&7))*8);
      }
      #pragma unroll
      for(int j=0;j<4;j++){
        int nl = wn + j*16 + l15;
        bf[j] = *(half8*)(Bs + nl*64 + (((ks<<2)|quad) ^ (nl&7))*8);
      }
      #pragma unroll
      for(int i=0;i<4;i++)
        #pragma unroll
        for(int j=0;j<4;j++)
          acc[i][j] = __builtin_amdgcn_mfma_f32_16x16x32_f16(af[i], bf[j], acc[i][j], 0,0,0);
    }
    __syncthreads();
  }
  #pragma unroll
  for(int i=0;i<4;i++){
    #pragma unroll
    for(int r=0;r<4;r++){
      int m = m0 + wm + i*16 + quad*4 + r;
      #pragma unroll
      for(int j=0;j<4;j++){
        int n = n0 + wn + j*16 + l15;
        unsafeAtomicAdd(&G[(size_t)m*EMBD + n], acc[i][j][r]);
      }
    }
  }
}

// ---- T = Wh * G (G symmetric, fp32; convert inline), no-LDS MFMA ----
//      one wave per 64x64 output tile: grid (12, 32) x 64 threads (confirmed win, r7/r8/r9)
__global__ __launch_bounds__(64) void k_gemmTh(const _Float16* __restrict__ Wh, const float* __restrict__ G,
                                               float* Tm){
  int lane = threadIdx.x & 63;
  int quad = lane>>4, l15 = lane&15;
  int n0 = blockIdx.x*64;
  int m0 = blockIdx.y*64;
  f32x4 acc[4][4];
  #pragma unroll
  for(int i=0;i<4;i++)
    #pragma unroll
    for(int j=0;j<4;j++) acc[i][j] = (f32x4){0.f,0.f,0.f,0.f};
  const _Float16* aB[4]; const float* bB[4];
  #pragma unroll
  for(int i=0;i<4;i++){
    aB[i] = Wh + (size_t)(m0+i*16+l15)*EMBD + quad*8;
    bB[i] = G  + (size_t)(n0+i*16+l15)*EMBD + quad*8;
  }
  for(int ks=0; ks<24; ks++){
    half8 af[4], bf[4];
    #pragma unroll
    for(int i=0;i<4;i++) af[i] = *(const half8*)(aB[i] + ks*32);
    #pragma unroll
    for(int j=0;j<4;j++){
      float4 f0 = *(const float4*)(bB[j] + ks*32);
      float4 f1 = *(const float4*)(bB[j] + ks*32 + 4);
      half8 h = {(_Float16)f0.x,(_Float16)f0.y,(_Float16)f0.z,(_Float16)f0.w,
                 (_Float16)f1.x,(_Float16)f1.y,(_Float16)f1.z,(_Float16)f1.w};
      bf[j] = h;
    }
    #pragma unroll
    for(int i=0;i<4;i++)
      #pragma unroll
      for(int j=0;j<4;j++)
        acc[i][j] = __builtin_amdgcn_mfma_f32_16x16x32_f16(af[i], bf[j], acc[i][j], 0,0,0);
  }
  #pragma unroll
  for(int i=0;i<4;i++)
    #pragma unroll
    for(int r=0;r<4;r++){
      int mg = m0 + i*16 + quad*4 + r;
      #pragma unroll
      for(int j=0;j<4;j++)
        Tm[(size_t)mg*EMBD + n0 + j*16 + l15] = acc[i][j][r];
    }
}

// ---- per-row closed-form stats ----
__global__ __launch_bounds__(256) void k_rowstats(const _Float16* __restrict__ Wh, const float* __restrict__ Tm,
      const _Float16* __restrict__ Eh, const float* __restrict__ qn, const float* __restrict__ cvec,
      const int* __restrict__ tp, const float* __restrict__ Svec, const float* __restrict__ Pvec,
      const float* __restrict__ QQ, float* alpha, float* betav){
  int row = blockIdx.x*4 + (threadIdx.x>>6);
  int lane = threadIdx.x & 63;
  if(row >= 2*B_PAIR) return;
  int pi = row & (B_PAIR-1);
  int lp = tp[2*pi], rp = tp[2*pi+1];
  float d1=0,d2=0,d3=0,dl=0,dr=0;
  #pragma unroll
  for(int k=0;k<12;k++){
    int d = lane + 64*k;
    float a = (float)Wh[(size_t)row*EMBD + d];
    d1 += a*Svec[d];
    d2 += a*Pvec[d];
    d3 += a*Tm[(size_t)row*EMBD + d];
    dl += a*(float)Eh[(size_t)lp*EMBD + d];
    dr += a*(float)Eh[(size_t)rp*EMBD + d];
  }
  d1=waveRedSum(d1); d2=waveRedSum(d2); d3=waveRedSum(d3);
  dl=waveRedSum(dl); dr=waveRedSum(dr);
  if(lane==0){
    double c = (double)cvec[row], Q = (double)QQ[0], Q2 = (double)QQ[1], Nn = (double)N_ENT;
    double su  = Nn*c - Q + 2.0*(double)d1;
    double su2 = Nn*c*c - 2.0*c*Q + Q2 + 4.0*(c*(double)d1 - (double)d2) + 4.0*(double)d3;
    double ul = c - (double)qn[lp] + 2.0*(double)dl;
    double ur = c - (double)qn[rp] + 2.0*(double)dr;
    su -= ul + ur;
    if(lp != rp) su2 -= ul*ul + ur*ur;
    double mu = su/Nn;
    double var = su2/Nn - mu*mu;
    double sd = sqrt(fmax(var, 0.0));
    double al = 20.0/sd;
    alpha[row] = (float)al;
    betav[row] = (float)(8.0 - al*mu);
  }
}

__device__ inline void lseMerge(float& mx, float& sm, float om, float os){
  if(om > mx){ sm = sm*expf(mx-om) + os; mx = om; }
  else if(om != -INFINITY){ sm += os*expf(om-mx); }
}

// ---- pass B: 128x128 f16 MFMA (DMA staging + XOR swizzle), two-pass masked-LSE epilogue.
//      Epilogue math: al>0 and (al,be) row-constant across the 16 lanes of a row, so encode
//      the mask into u (u'=0 -> z=be; lp==rp -> u'=-u): max z = al*max(u')+be and
//      sm = sum exp(al*(u'-umax)). NOTE: exp arg MUST be al*(u-umax), never
//      fmaf(al,u,-al*umax) -- fmaf's exact product vs the rounded t gives arg up to
//      +ulp(al*1e30) ~ +2e25 on pad columns -> expf=inf -> inf*0=NaN downstream (r4 failure).
//      u-umax <= 0 is guaranteed by fmaxf, so exp arg <= 0 always.
//      __launch_bounds__(256,3) is the MEASURED register-allocation sweet spot (r5/r7/r8/r9 arc):
//        (256,3): VGPR 64 (+64 AGPR = 128/wave, budget 170) -> 3 blk/CU, 40% occ, 138us.
//        (256,5): budget 102 < 128 footprint -> acc spills to scratch, WRITE 31->760MB, 341us.
//        (256):   no bound -> allocator bloats to 88 VGPR -> ~2 blk/CU, 21.6% occ, 224us.
//      Do not change this clause without re-measuring VGPR_Count + WRITE_SIZE.
//      1D grid 3840, XCD-ownership: id = xcd + 8*m + 128*tt -> ntile = xcd + 8*tt.
__global__ __launch_bounds__(256,3) void k_gemmB(const _Float16* __restrict__ Wh, const _Float16* __restrict__ Eh,
    const float* __restrict__ cvec, const float* __restrict__ qn, const int* __restrict__ tp,
    const float* __restrict__ alpha, const float* __restrict__ betav, float* pm, float* ps){
  __shared__ __align__(16) _Float16 As[128*64];
  __shared__ __align__(16) _Float16 Bs[128*64];
  int id = blockIdx.x;
  int ntile = (id & 7) + ((id >> 7) << 3);
  int m0 = ((id >> 3) & 15) * 128;
  int n0 = ntile * 128;
  int tid = threadIdx.x;
  int w = tid>>6, lane = tid&63;
  int quad = lane>>4, l15 = lane&15;
  int lr = lane>>3, lc = lane&7;
  int wm = (w&1)*64, wn = (w>>1)*64;
  f32x4 acc[4][4];
  #pragma unroll
  for(int i=0;i<4;i++)
    #pragma unroll
    for(int j=0;j<4;j++) acc[i][j] = (f32x4){0.f,0.f,0.f,0.f};
  for(int k0=0;k0<EMBD;k0+=64){
    #pragma unroll
    for(int p=0;p<4;p++){
      int r = p*32 + w*8 + lr;
      int cg = lc ^ (r&7);
      gl_lds16(Wh + (size_t)(m0+r)*EMBD + k0 + cg*8, As + (p*32 + w*8)*64);
      gl_lds16(Eh + (size_t)(n0+r)*EMBD + k0 + cg*8, Bs + (p*32 + w*8)*64);
    }
    __syncthreads();
    #pragma unroll
    for(int ks=0;ks<2;ks++){
      half8 af[4], bf[4];
      #pragma unroll
      for(int i=0;i<4;i++){
        int ml = wm + i*16 + l15;
        af[i] = *(half8*)(As + ml*64 + (((ks<<2)|quad) ^ (ml&7))*8);
      }
      #pragma unroll
      for(int j=0;j<4;j++){
        int nl = wn + j*16 + l15;
        bf[j] = *(half8*)(Bs + nl*64 + (((ks<<2)|quad) ^ (nl&7))*8);
      }
      #pragma unroll
      for(int i=0;i<4;i++)
        #pragma unroll
        for(int j=0;j<4;j++)
          acc[i][j] = __builtin_amdgcn_mfma_f32_16x16x32_f16(af[i], bf[j], acc[i][j], 0,0,0);
    }
    __syncthreads();
  }
  // epilogue: two-pass masked LSE over this wave's 64 cols; fmax/add butterflies over 16 lanes/row.
  float qv[4]; int jv[4];
  #pragma unroll
  for(int j=0;j<4;j++){ jv[j] = n0 + wn + j*16 + l15; qv[j] = qn[jv[j]]; }
  int ptile = ntile*2 + (w>>1);
  #pragma unroll
  for(int i=0;i<4;i++){
    int mbase = m0 + wm + i*16 + quad*4;
    #pragma unroll
    for(int r=0;r<4;r++){
      int mg = mbase + r;
      int pi = mg & (B_PAIR-1);
      int lp = tp[2*pi], rp = tp[2*pi+1];
      float cv = cvec[mg], al = alpha[mg], be = betav[mg];
      float u[4];
      #pragma unroll
      for(int j=0;j<4;j++){
        float uu = fmaf(2.f, acc[i][j][r], cv - qv[j]);
        if(jv[j]==lp || jv[j]==rp) uu = (lp==rp) ? -uu : 0.f;
        u[j] = uu;
      }
      float umax = fmaxf(fmaxf(u[0],u[1]), fmaxf(u[2],u[3]));
      #pragma unroll
      for(int m=8;m>=1;m>>=1) umax = fmaxf(umax, __shfl_xor(umax, m, 64));
      float s = __expf(al*(u[0]-umax)) + __expf(al*(u[1]-umax))
              + __expf(al*(u[2]-umax)) + __expf(al*(u[3]-umax));
      #pragma unroll
      for(int m=8;m>=1;m>>=1) s += __shfl_xor(s, m, 64);
      if(l15==0){ pm[(size_t)mg*PTILES + ptile] = fmaf(al, umax, be); ps[(size_t)mg*PTILES + ptile] = s; }
    }
  }
}

// ---- combine per-tile LSE partials + fused final mean via atomic ticket: block per row ----
__global__ __launch_bounds__(256) void k_lse2(const float* __restrict__ pm, const float* __restrict__ ps,
                        float* accum, int* done, float* out){
  __shared__ float shm[256], shs[256];
  int row = blockIdx.x, tid = threadIdx.x;
  float mx = -INFINITY, sm = 0.f;
  for(int t=tid;t<PTILES;t+=256) lseMerge(mx, sm, pm[(size_t)row*PTILES+t], ps[(size_t)row*PTILES+t]);
  shm[tid]=mx; shs[tid]=sm;
  __syncthreads();
  for(int w=128;w>0;w>>=1){
    if(tid<w){
      float m2=shm[tid], s2=shs[tid];
      lseMerge(m2, s2, shm[tid+w], shs[tid+w]);
      shm[tid]=m2; shs[tid]=s2;
    }
    __syncthreads();
  }
  if(tid==0){
    float l = shm[0] + logf(shs[0]);
    atomicAdd(accum, l);
    __threadfence();
    int t = atomicAdd(done, 1);
    if(t == 2*B_PAIR - 1){
      __threadfence();
      float total = atomicAdd(accum, 0.0f);
      out[0] = total / (float)B_PAIR;
    }
  }
}

extern "C" void kernel_launch(void* const* d_in, const int* in_sizes, int n_in,
                              void* d_out, int out_size, void* d_ws, size_t ws_size,
                              hipStream_t stream) {
  const float* ent_emb = (const float*)d_in[0];
  const float* rel_emb = (const float*)d_in[1];
  const float* attn_e  = (const float*)d_in[2];
  const float* attn_r  = (const float*)d_in[3];
  const int* adj     = (const int*)d_in[5];
  const int* r_index = (const int*)d_in[6];
  const int* ent_adj = (const int*)d_in[7];
  const int* rel_adj = (const int*)d_in[8];
  const int* tp      = (const int*)d_in[9];
  float* out = (float*)d_out;

  const int* adj_row = adj;
  const int* adj_col = adj + T_EDGE;
  const int* rid1    = r_index + T_EDGE;

  char* base = (char*)d_ws;
  size_t off = 0;
  auto A = [&](size_t b)->void*{ void* p = base + off; off = (off + b + 255) & ~(size_t)255; return p; };
  // zero region
  int*   cntA  = (int*)  A((size_t)N_ENT*4);
  int*   cntE  = (int*)  A((size_t)N_ENT*4);
  int*   cntR  = (int*)  A((size_t)N_ENT*4);
  float* G     = (float*)A((size_t)EMBD*EMBD*4);
  float* Svec  = (float*)A(EMBD*4);
  float* Pvec  = (float*)A(EMBD*4);
  float* QQ    = (float*)A(2*4);
  float* accum = (float*)A(4);
  int*   done  = (int*)  A(4);
  size_t zero_end = off;
  // plain buffers
  int* startA = (int*)A((size_t)(N_ENT+1)*4);
  int* startE = (int*)A((size_t)(N_ENT+1)*4);
  int* startR = (int*)A((size_t)(N_ENT+1)*4);
  int* curA   = (int*)A((size_t)N_ENT*4);
  int* curE   = (int*)A((size_t)N_ENT*4);
  int* curR   = (int*)A((size_t)N_ENT*4);
  int* part   = (int*)A(3*SCB*4);
  int* tots   = (int*)A(3*4);
  int2* sAB   = (int2*)A((size_t)T_EDGE*8);
  int* scolE  = (int*)A((size_t)NNZ_E*4);
  int* scolR  = (int*)A((size_t)NNZ_E*4);
  _Float16* Eh = (_Float16*)A((size_t)NPAD*EMBD*2);   // pad rows zeroed in k_prep
  // region X: phase-aliased (featC0/featC1 -> embT -> pm/ps)
  char* X = (char*)A((size_t)EMBD*NPAD*2);   // 47.2 MB
  _Float16* featC0 = (_Float16*)X;                       // 15.4 MB
  _Float16* featC1 = (_Float16*)(X + 16u*1024u*1024u);   // 15.4 MB
  _Float16* embT   = (_Float16*)X;
  float*    pm     = (float*)X;                          // 2048*480*4 = 3.93 MB
  float*    ps     = (float*)(X + 8u*1024u*1024u);
  _Float16* relnH  = (_Float16*)A((size_t)R_REL*128*2);
  _Float16* ehE   = (_Float16*)A((size_t)N_ENT*128*2);
  _Float16* ehR   = (_Float16*)A((size_t)R_REL*128*2);
  float* expdot  = (float*)A(4*R_REL*4);
  _Float16* Wh   = (_Float16*)A((size_t)2*B_PAIR*EMBD*2);
  float* Tm      = (float*)A((size_t)2*B_PAIR*EMBD*4);
  float* cvec    = (float*)A(2*B_PAIR*4);
  float* qn      = (float*)A((size_t)NPAD*4);
  float* alpha   = (float*)A(2*B_PAIR*4);
  float* betav   = (float*)A(2*B_PAIR*4);
  (void)ws_size; (void)in_sizes; (void)n_in; (void)out_size;

  hipMemsetAsync(d_ws, 0, zero_end, stream);

  // ---- fused prep: fp16 conversion + Eh pad zero + relnorm/expdot + edge counts ----
  k_prep<<<(N_ENT*128+255)/256, 256, 0, stream>>>(ent_emb, rel_emb, attn_e, attn_r,
                                                  ehE, ehR, Eh, relnH, expdot,
                                                  adj_row, cntA, ent_adj, cntE, rel_adj, cntR);

  // ---- parallel 3-phase scan ----
  dim3 gsa(SCB, 3);
  k_scanA<<<gsa, 256, 0, stream>>>(cntA, cntE, cntR, startA, startE, startR, part);
  k_scanB<<<1, 256, 0, stream>>>(part, tots);
  k_scanC<<<gsa, 256, 0, stream>>>(startA, startE, startR, curA, curE, curR, part, tots);
  k_scatter3<<<(NNZ_E+255)/256, 256, 0, stream>>>(adj_row, adj_col, rid1, curA, sAB,
                                                  ent_adj, ent_adj+NNZ_E, curE, scolE,
                                                  rel_adj, rel_adj+NNZ_E, curR, scolR);

  // ---- fused dual GAT stack: avg (ent|rel merged) -> layer0 -> layer1 ----
  dim3 gavg(N_ENT/4, 2);
  k_avg2<<<gavg, 256, 0, stream>>>(startE, scolE, ehE, startR, scolR, ehR, featC0, Eh);
  k_edge2<<<N_ENT/4, 256, 0, stream>>>(startA, sAB, relnH, expdot + 0*R_REL, expdot + 2*R_REL,
                                       featC0, featC1, Eh, 128, 512);
  k_edge2<<<N_ENT/4, 256, 0, stream>>>(startA, sAB, relnH, expdot + 1*R_REL, expdot + 3*R_REL,
                                       featC1, featC0, Eh, 256, 640);

  // ---- fused post pass: transp | gather | qnstats ----
  k_post<<<5760 + B_PAIR + 240, 256, 0, stream>>>(Eh, embT, tp, Wh, cvec, qn, Svec, Pvec, QQ);

  // ---- align loss ----
  k_syrk<<<1152, 256, 0, stream>>>(embT, G);
  dim3 gT(EMBD/64, 32);
  k_gemmTh<<<gT, 64, 0, stream>>>(Wh, G, Tm);
  k_rowstats<<<2*B_PAIR/4, 256, 0, stream>>>(Wh, Tm, Eh, qn, cvec, tp, Svec, Pvec, QQ, alpha, betav);
  k_gemmB<<<NT128*16, 256, 0, stream>>>(Wh, Eh, cvec, qn, tp, alpha, betav, pm, ps);
  k_lse2<<<2*B_PAIR, 256, 0, stream>>>(pm, ps, accum, done, out);
}

// Round 14
// 770.555 us; speedup vs baseline: 1.0346x; 1.0346x over previous
//
#include <hip/hip_runtime.h>
#include <math.h>

#define N_ENT 30000
#define R_REL 1000
#define T_EDGE 300000
#define B_PAIR 1024
#define NNZ_E 600000
#define GAMMAF 3.0f
#define EPSV 1e-12f
#define EMBD 768
#define NPAD 30720           // N_ENT padded to 240 tiles of 128 (zeroed pad rows in Eh; qn[pad]=1e30)
#define NT128 240            // n-tiles of 128 for gemmB
#define PTILES 480           // lse partial tiles per row (2 per 128-tile)
#define SCB 118              // scan blocks per list (118*256 >= 30000)

typedef _Float16 half8 __attribute__((ext_vector_type(8)));
typedef _Float16 half4v __attribute__((ext_vector_type(4)));
typedef _Float16 half2v __attribute__((ext_vector_type(2)));
typedef float f32x4 __attribute__((ext_vector_type(4)));

__device__ inline void gl_lds16(const _Float16* g, _Float16* l){
  __builtin_amdgcn_global_load_lds(
      (const __attribute__((address_space(1))) unsigned int*)g,
      (__attribute__((address_space(3))) unsigned int*)l, 16, 0, 0);
}

__device__ inline float waveRedSum(float v){
  #pragma unroll
  for(int m=32;m>=1;m>>=1) v += __shfl_xor(v, m, 64);
  return v;
}

__device__ inline float fast_tanh(float x){
  x = fminf(10.f, fmaxf(-10.f, x));
  float e = __expf(2.f*x);
  return (e-1.f)/(e+1.f);
}

// ---- fused prep: fp16 convert embeddings + zero Eh pad rows + relnorm/expdot + edge counts ----
__global__ __launch_bounds__(256) void k_prep(const float* __restrict__ ent, const float* __restrict__ rel,
      const float* __restrict__ ae, const float* __restrict__ ar,
      _Float16* ehE, _Float16* ehR, _Float16* Eh, _Float16* relnH, float* expdot,
      const int* __restrict__ rA, int* cA, const int* __restrict__ rE, int* cE,
      const int* __restrict__ rR, int* cR){
  int i = blockIdx.x*256 + threadIdx.x;
  if(i < N_ENT*128) ehE[i] = (_Float16)ent[i];
  if(i < R_REL*128) ehR[i] = (_Float16)rel[i];
  if(i < (NPAD-N_ENT)*EMBD) Eh[(size_t)N_ENT*EMBD + i] = (_Float16)0.f;
  if(i < T_EDGE) atomicAdd(&cA[rA[i]], 1);
  if(i < NNZ_E){ atomicAdd(&cE[rE[i]], 1); atomicAdd(&cR[rR[i]], 1); }
  int r = i >> 6;
  if(r < R_REL){
    int lane = i & 63;
    float2 v = *(const float2*)(rel + (size_t)r*128 + lane*2);
    float ss = waveRedSum(v.x*v.x + v.y*v.y);
    float nrm = fmaxf(sqrtf(ss), EPSV);
    float2 u; u.x = v.x/nrm; u.y = v.y/nrm;
    half2v uh = {(_Float16)u.x, (_Float16)u.y};
    *(half2v*)(relnH + (size_t)r*128 + lane*2) = uh;
    const float* ks[4] = {ae, ae+128, ar, ar+128};   // ent l0, ent l1, rel l0, rel l1
    #pragma unroll
    for(int k=0;k<4;k++){
      float2 w = *(const float2*)(ks[k] + lane*2);
      float d = waveRedSum(u.x*w.x + u.y*w.y);
      if(lane==0) expdot[k*R_REL + r] = __expf(d);
    }
  }
}

// ---- scan phase A: per-block exclusive scan + block totals; grid (SCB, 3) ----
__global__ __launch_bounds__(256) void k_scanA(const int* c0, const int* c1, const int* c2,
                                               int* s0, int* s1, int* s2, int* part){
  const int* cnt = blockIdx.y==0 ? c0 : (blockIdx.y==1 ? c1 : c2);
  int* start     = blockIdx.y==0 ? s0 : (blockIdx.y==1 ? s1 : s2);
  __shared__ int wsum[4];
  int i = blockIdx.x*256 + threadIdx.x;
  int lane = threadIdx.x & 63, wid = threadIdx.x >> 6;
  int v = (i < N_ENT) ? cnt[i] : 0;
  int x = v;
  #pragma unroll
  for(int off=1; off<64; off<<=1){ int t=__shfl_up(x,off,64); if(lane>=off) x+=t; }
  if(lane==63) wsum[wid] = x;
  __syncthreads();
  int woff = 0;
  #pragma unroll
  for(int k=0;k<3;k++) if(k < wid) woff += wsum[k];
  if(i < N_ENT) start[i] = woff + x - v;
  if(threadIdx.x == 255) part[blockIdx.y*SCB + blockIdx.x] = woff + x;
}

// ---- scan phase B: 1 block; wave per list scans SCB partials ----
__global__ __launch_bounds__(256) void k_scanB(int* part, int* tots){
  int wid = threadIdx.x>>6, lane = threadIdx.x&63;
  if(wid >= 3) return;
  int base = wid*SCB;
  int v0 = part[base + lane];
  int i1 = 64 + lane;
  int v1 = (i1 < SCB) ? part[base + i1] : 0;
  int x0 = v0, x1 = v1;
  #pragma unroll
  for(int off=1; off<64; off<<=1){
    int t0=__shfl_up(x0,off,64), t1=__shfl_up(x1,off,64);
    if(lane>=off){ x0+=t0; x1+=t1; }
  }
  int t0 = __shfl(x0, 63, 64);
  int t1 = __shfl(x1, 63, 64);
  part[base + lane] = x0 - v0;
  if(i1 < SCB) part[base + i1] = t0 + x1 - v1;
  if(lane == 0) tots[wid] = t0 + t1;
}

// ---- scan phase C: add block offsets, write cursor + totals ----
__global__ __launch_bounds__(256) void k_scanC(int* s0, int* s1, int* s2,
                                               int* u0, int* u1, int* u2,
                                               const int* part, const int* tots){
  int y = blockIdx.y;
  int* start  = y==0 ? s0 : (y==1 ? s1 : s2);
  int* cursor = y==0 ? u0 : (y==1 ? u1 : u2);
  int i = blockIdx.x*256 + threadIdx.x;
  int off = part[y*SCB + blockIdx.x];
  if(i < N_ENT){ int v = start[i] + off; start[i] = v; cursor[i] = v; }
  if(i == 0) start[N_ENT] = tots[y];
}

// ---- scatter all three edge lists into CSR order, one launch ----
//      (r13 A/B note: packing scolA+sridA into one int2 store cut scatter below the top-5
//      window but total regressed 778.5->797; reverted to the twice-measured-best layout.
//      k_scatter3 is write-amplification-bound: 108MB WRITE for ~7MB payload -- random 4B
//      stores each dirty a 64B line. This is the structural floor for count-sort scatter.)
__global__ __launch_bounds__(256) void k_scatter3(
      const int* __restrict__ rA, const int* __restrict__ cAj, const int* __restrict__ rid,
      int* uA, int* scolA, int* sridA,
      const int* __restrict__ rE, const int* __restrict__ cEj, int* uE, int* scolE,
      const int* __restrict__ rR, const int* __restrict__ cRj, int* uR, int* scolR){
  int e = blockIdx.x*256 + threadIdx.x;
  if(e < T_EDGE){
    int p = atomicAdd(&uA[rA[e]], 1);
    scolA[p] = cAj[e];
    sridA[p] = rid[e];
  }
  if(e < NNZ_E){
    int p = atomicAdd(&uE[rE[e]], 1);
    scolE[p] = cEj[e];
    int q = atomicAdd(&uR[rR[e]], 1);
    scolR[q] = cRj[e];
  }
}

// ---- _avg via CSR gather from fp16 src (ent: y=0, rel: y=1), fused tanh ----
//      2-edge unroll is the measured optimum: r10's 4-edge unroll regressed total 780->822
//      (mean degree ~10-20 -> bigger scalar tail + register pressure). Keep 2-wide.
__global__ __launch_bounds__(256) void k_avg2(const int* __restrict__ startE, const int* __restrict__ scolE,
                        const _Float16* __restrict__ srcE,
                        const int* __restrict__ startR, const int* __restrict__ scolR,
                        const _Float16* __restrict__ srcR,
                        _Float16* featC, _Float16* Eh){
  int which = blockIdx.y;
  const int* start = which? startR : startE;
  const int* scol  = which? scolR : scolE;
  const _Float16* src = which? srcR : srcE;
  int pairOff = which? 2 : 0;
  int coloff  = which? 384 : 0;
  int r = blockIdx.x*4 + (threadIdx.x>>6);
  int lane = threadIdx.x & 63;
  int s0 = start[r], s1 = start[r+1];
  float ax=0.f, ay=0.f;
  int e = s0;
  for(; e+1<s1; e+=2){
    int c0 = scol[e], c1 = scol[e+1];
    half2v v0 = *(const half2v*)(src + (size_t)c0*128 + lane*2);
    half2v v1 = *(const half2v*)(src + (size_t)c1*128 + lane*2);
    ax += (float)v0[0] + (float)v1[0]; ay += (float)v0[1] + (float)v1[1];
  }
  if(e<s1){
    int c0 = scol[e];
    half2v v0 = *(const half2v*)(src + (size_t)c0*128 + lane*2);
    ax += (float)v0[0]; ay += (float)v0[1];
  }
  float inv = (s1>s0) ? 1.0f/(float)(s1-s0) : 0.f;
  float vx = fast_tanh(ax*inv), vy = fast_tanh(ay*inv);
  half2v hv = {(_Float16)vx, (_Float16)vy};
  *(half2v*)(featC + (size_t)r*256 + lane*4 + pairOff) = hv;
  *(half2v*)(Eh + (size_t)r*EMBD + coloff + lane*2) = hv;
}

// ---- fused dual-stack GAT layer: one pass does ent+rel Householder+softmax ----
//      2-edge unroll is the measured optimum (r10 4-wide regressed +42us).
__global__ __launch_bounds__(256) void k_edge2(const int* __restrict__ start, const int* __restrict__ scol,
      const int* __restrict__ srid, const _Float16* __restrict__ relnH,
      const float* __restrict__ expE, const float* __restrict__ expR,
      const _Float16* __restrict__ featIn, _Float16* featOut, _Float16* Eh, int colEnt, int colRel){
  int r = blockIdx.x*4 + (threadIdx.x>>6);
  int lane = threadIdx.x & 63;
  int s0 = start[r], s1 = start[r+1];
  float aEx=0,aEy=0,aRx=0,aRy=0, swE=0, swR=0;
  int e = s0;
  for(; e+1<s1; e+=2){
    int c0=scol[e], q0=srid[e], c1=scol[e+1], q1=srid[e+1];
    float wE0=expE[q0], wR0=expR[q0], wE1=expE[q1], wR1=expR[q1];
    half2v u0h = *(const half2v*)(relnH + (size_t)q0*128 + lane*2);
    half2v u1h = *(const half2v*)(relnH + (size_t)q1*128 + lane*2);
    half4v h0 = *(const half4v*)(featIn + (size_t)c0*256 + lane*4);
    half4v h1 = *(const half4v*)(featIn + (size_t)c1*256 + lane*4);
    float u0x=(float)u0h[0], u0y=(float)u0h[1], u1x=(float)u1h[0], u1y=(float)u1h[1];
    float e0x=(float)h0[0], e0y=(float)h0[1], r0x=(float)h0[2], r0y=(float)h0[3];
    float e1x=(float)h1[0], e1y=(float)h1[1], r1x=(float)h1[2], r1y=(float)h1[3];
    float d0 = e0x*u0x + e0y*u0y;
    float d1 = r0x*u0x + r0y*u0y;
    float d2 = e1x*u1x + e1y*u1y;
    float d3 = r1x*u1x + r1y*u1y;
    #pragma unroll
    for(int m=32;m>=1;m>>=1){
      d0 += __shfl_xor(d0,m,64); d1 += __shfl_xor(d1,m,64);
      d2 += __shfl_xor(d2,m,64); d3 += __shfl_xor(d3,m,64);
    }
    aEx += wE0*(e0x - 2.f*d0*u0x) + wE1*(e1x - 2.f*d2*u1x);
    aEy += wE0*(e0y - 2.f*d0*u0y) + wE1*(e1y - 2.f*d2*u1y);
    aRx += wR0*(r0x - 2.f*d1*u0x) + wR1*(r1x - 2.f*d3*u1x);
    aRy += wR0*(r0y - 2.f*d1*u0y) + wR1*(r1y - 2.f*d3*u1y);
    swE += wE0+wE1; swR += wR0+wR1;
  }
  if(e<s1){
    int c0=scol[e], q0=srid[e];
    float wE0=expE[q0], wR0=expR[q0];
    half2v u0h = *(const half2v*)(relnH + (size_t)q0*128 + lane*2);
    half4v h0 = *(const half4v*)(featIn + (size_t)c0*256 + lane*4);
    float u0x=(float)u0h[0], u0y=(float)u0h[1];
    float e0x=(float)h0[0], e0y=(float)h0[1], r0x=(float)h0[2], r0y=(float)h0[3];
    float d0 = e0x*u0x + e0y*u0y;
    float d1 = r0x*u0x + r0y*u0y;
    #pragma unroll
    for(int m=32;m>=1;m>>=1){ d0 += __shfl_xor(d0,m,64); d1 += __shfl_xor(d1,m,64); }
    aEx += wE0*(e0x - 2.f*d0*u0x);
    aEy += wE0*(e0y - 2.f*d0*u0y);
    aRx += wR0*(r0x - 2.f*d1*u0x);
    aRy += wR0*(r0y - 2.f*d1*u0y);
    swE += wE0; swR += wR0;
  }
  float iE = (s1>s0) ? 1.f/swE : 0.f;
  float iR = (s1>s0) ? 1.f/swR : 0.f;
  float vEx = fast_tanh(aEx*iE), vEy = fast_tanh(aEy*iE);
  float vRx = fast_tanh(aRx*iR), vRy = fast_tanh(aRy*iR);
  half4v ov = {(_Float16)vEx,(_Float16)vEy,(_Float16)vRx,(_Float16)vRy};
  *(half4v*)(featOut + (size_t)r*256 + lane*4) = ov;
  half2v he = {(_Float16)vEx,(_Float16)vEy};
  half2v hr = {(_Float16)vRx,(_Float16)vRy};
  *(half2v*)(Eh + (size_t)r*EMBD + colEnt + lane*2) = he;
  *(half2v*)(Eh + (size_t)r*EMBD + colRel + lane*2) = hr;
}

// ---- fused post-GAT pass: transp (b<5760) | gather (b<6784) | qnstats (b<7024) ----
__global__ __launch_bounds__(256) void k_post(const _Float16* __restrict__ Eh, _Float16* embT,
      const int* __restrict__ tp, _Float16* Wh, float* cvec,
      float* qn, float* Svec, float* Pvec, float* QQ){
  __shared__ __align__(16) _Float16 til[64][72];
  __shared__ float sh0[256], sh1[256], sh2[256];
  int b = blockIdx.x;
  int tid = threadIdx.x;
  if(b < 5760){
    // ---- transpose Eh -> embT (768 x NPAD) ----
    int r0 = (b % 480)*64, c0 = (b / 480)*64;
    int rr = tid>>3, c8 = (tid&7)*8;
    #pragma unroll
    for(int p=0;p<2;p++){
      int gr = r0 + rr + p*32;
      uint4 v = make_uint4(0u,0u,0u,0u);
      if(gr < N_ENT) v = *(const uint4*)(Eh + (size_t)gr*EMBD + c0 + c8);
      *(uint4*)&til[rr + p*32][c8] = v;
    }
    __syncthreads();
    #pragma unroll
    for(int p=0;p<2;p++){
      int cc = rr + p*32;
      __align__(16) _Float16 tmp[8];
      #pragma unroll
      for(int j=0;j<8;j++) tmp[j] = til[c8 + j][cc];
      *(uint4*)(embT + (size_t)(c0+cc)*NPAD + r0 + c8) = *(uint4*)tmp;
    }
  } else if(b < 5760 + B_PAIR){
    // ---- gather pair rows -> Wh, cvec ----
    int i = b - 5760;
    int l = tp[2*i], r = tp[2*i+1];
    float sl=0.f, sr=0.f, sp=0.f;
    for(int c=tid;c<EMBD;c+=256){
      _Float16 lh = Eh[(size_t)l*EMBD+c], rh = Eh[(size_t)r*EMBD+c];
      float le = (float)lh, re = (float)rh;
      Wh[(size_t)i*EMBD+c]=lh; Wh[(size_t)(B_PAIR+i)*EMBD+c]=rh;
      sl += le*le; sr += re*re; float d = le-re; sp += d*d;
    }
    sh0[tid]=sl; sh1[tid]=sr; sh2[tid]=sp;
    __syncthreads();
    for(int w=128;w>0;w>>=1){
      if(tid<w){ sh0[tid]+=sh0[tid+w]; sh1[tid]+=sh1[tid+w]; sh2[tid]+=sh2[tid+w]; }
      __syncthreads();
    }
    if(tid==0){
      float pos = sh2[0];
      cvec[i]        = pos + GAMMAF - sh0[0];
      cvec[B_PAIR+i] = pos + GAMMAF - sh1[0];
    }
  } else {
    // ---- qn + embstats: wave per row, strided over 960 waves ----
    int wid = tid>>6, lane = tid&63;
    int gw = (b - 5760 - B_PAIR)*4 + wid;
    float s[12], p[12];
    #pragma unroll
    for(int q=0;q<12;q++){ s[q]=0.f; p[q]=0.f; }
    float q1=0.f, q2=0.f;
    for(int r=gw; r<NPAD; r+=960){
      if(r >= N_ENT){ if(lane==0) qn[r] = 1e30f; continue; }
      float v[12]; float ss=0.f;
      #pragma unroll
      for(int q=0;q<12;q++){ v[q] = (float)Eh[(size_t)r*EMBD + lane + 64*q]; ss += v[q]*v[q]; }
      ss = waveRedSum(ss);
      ss = __shfl(ss, 0, 64);
      if(lane==0){ qn[r] = ss; q1 += ss; q2 += ss*ss; }
      #pragma unroll
      for(int q=0;q<12;q++){ s[q] += v[q]; p[q] += ss*v[q]; }
    }
    #pragma unroll
    for(int q=0;q<12;q++){
      unsafeAtomicAdd(&Svec[lane + 64*q], s[q]);
      unsafeAtomicAdd(&Pvec[lane + 64*q], p[q]);
    }
    if(lane==0){ unsafeAtomicAdd(&QQ[0], q1); unsafeAtomicAdd(&QQ[1], q2); }
  }
}

// ---- G = E^T E via f16 MFMA on embT; 128x128 tiles, split-K 32 with XCD-owned k-slices ----
//      grid 1152: xcd = id&7, rest = id>>3 (0..143); kslice = xcd + 8*(rest/36) in [0,32); tile = rest%36
//      (confirmed win together with k_gemmTh regrid: ~-50us total, r7/r8/r9)
__global__ __launch_bounds__(256) void k_syrk(const _Float16* __restrict__ embT, float* G){
  __shared__ __align__(16) _Float16 As[128*64];
  __shared__ __align__(16) _Float16 Bs[128*64];
  int id = blockIdx.x;
  int xcd = id & 7, rest = id >> 3;
  int kslc = xcd + 8*(rest/36);
  int tile = rest % 36;
  int m0 = (tile/6)*128, n0 = (tile%6)*128;
  int kbeg = kslc*960, kend = kbeg + 960;
  int tid = threadIdx.x;
  int w = tid>>6, lane = tid&63;
  int quad = lane>>4, l15 = lane&15;
  int lr = lane>>3, lc = lane&7;
  int wm = (w>>1)*64, wn = (w&1)*64;
  f32x4 acc[4][4];
  #pragma unroll
  for(int i=0;i<4;i++)
    #pragma unroll
    for(int j=0;j<4;j++) acc[i][j] = (f32x4){0.f,0.f,0.f,0.f};
  for(int k0=kbeg;k0<kend;k0+=64){
    #pragma unroll
    for(int p=0;p<4;p++){
      int r = p*32 + w*8 + lr;
      int cg = lc ^ (r&7);
      gl_lds16(embT + (size_t)(m0+r)*NPAD + k0 + cg*8, As + (p*32 + w*8)*64);
      gl_lds16(embT + (size_t)(n0+r)*NPAD + k0 + cg*8, Bs + (p*32 + w*8)*64);
    }
    __syncthreads();
    #pragma unroll
    for(int ks=0;ks<2;ks++){
      half8 af[4], bf[4];
      #pragma unroll
      for(int i=0;i<4;i++){
        int ml = wm + i*16 + l15;
        af[i] = *(half8*)(As + ml*64 + (((ks<<2)|quad) ^ (ml&7))*8);
      }
      #pragma unroll
      for(int j=0;j<4;j++){
        int nl = wn + j*16 + l15;
        bf[j] = *(half8*)(Bs + nl*64 + (((ks<<2)|quad) ^ (nl&7))*8);
      }
      #pragma unroll
      for(int i=0;i<4;i++)
        #pragma unroll
        for(int j=0;j<4;j++)
          acc[i][j] = __builtin_amdgcn_mfma_f32_16x16x32_f16(af[i], bf[j], acc[i][j], 0,0,0);
    }
    __syncthreads();
  }
  #pragma unroll
  for(int i=0;i<4;i++){
    #pragma unroll
    for(int r=0;r<4;r++){
      int m = m0 + wm + i*16 + quad*4 + r;
      #pragma unroll
      for(int j=0;j<4;j++){
        int n = n0 + wn + j*16 + l15;
        unsafeAtomicAdd(&G[(size_t)m*EMBD + n], acc[i][j][r]);
      }
    }
  }
}

// ---- T = Wh * G (G symmetric, fp32; convert inline), no-LDS MFMA ----
//      one wave per 64x64 output tile: grid (12, 32) x 64 threads (confirmed win, r7/r8/r9)
__global__ __launch_bounds__(64) void k_gemmTh(const _Float16* __restrict__ Wh, const float* __restrict__ G,
                                               float* Tm){
  int lane = threadIdx.x & 63;
  int quad = lane>>4, l15 = lane&15;
  int n0 = blockIdx.x*64;
  int m0 = blockIdx.y*64;
  f32x4 acc[4][4];
  #pragma unroll
  for(int i=0;i<4;i++)
    #pragma unroll
    for(int j=0;j<4;j++) acc[i][j] = (f32x4){0.f,0.f,0.f,0.f};
  const _Float16* aB[4]; const float* bB[4];
  #pragma unroll
  for(int i=0;i<4;i++){
    aB[i] = Wh + (size_t)(m0+i*16+l15)*EMBD + quad*8;
    bB[i] = G  + (size_t)(n0+i*16+l15)*EMBD + quad*8;
  }
  for(int ks=0; ks<24; ks++){
    half8 af[4], bf[4];
    #pragma unroll
    for(int i=0;i<4;i++) af[i] = *(const half8*)(aB[i] + ks*32);
    #pragma unroll
    for(int j=0;j<4;j++){
      float4 f0 = *(const float4*)(bB[j] + ks*32);
      float4 f1 = *(const float4*)(bB[j] + ks*32 + 4);
      half8 h = {(_Float16)f0.x,(_Float16)f0.y,(_Float16)f0.z,(_Float16)f0.w,
                 (_Float16)f1.x,(_Float16)f1.y,(_Float16)f1.z,(_Float16)f1.w};
      bf[j] = h;
    }
    #pragma unroll
    for(int i=0;i<4;i++)
      #pragma unroll
      for(int j=0;j<4;j++)
        acc[i][j] = __builtin_amdgcn_mfma_f32_16x16x32_f16(af[i], bf[j], acc[i][j], 0,0,0);
  }
  #pragma unroll
  for(int i=0;i<4;i++)
    #pragma unroll
    for(int r=0;r<4;r++){
      int mg = m0 + i*16 + quad*4 + r;
      #pragma unroll
      for(int j=0;j<4;j++)
        Tm[(size_t)mg*EMBD + n0 + j*16 + l15] = acc[i][j][r];
    }
}

// ---- per-row closed-form stats ----
__global__ __launch_bounds__(256) void k_rowstats(const _Float16* __restrict__ Wh, const float* __restrict__ Tm,
      const _Float16* __restrict__ Eh, const float* __restrict__ qn, const float* __restrict__ cvec,
      const int* __restrict__ tp, const float* __restrict__ Svec, const float* __restrict__ Pvec,
      const float* __restrict__ QQ, float* alpha, float* betav){
  int row = blockIdx.x*4 + (threadIdx.x>>6);
  int lane = threadIdx.x & 63;
  if(row >= 2*B_PAIR) return;
  int pi = row & (B_PAIR-1);
  int lp = tp[2*pi], rp = tp[2*pi+1];
  float d1=0,d2=0,d3=0,dl=0,dr=0;
  #pragma unroll
  for(int k=0;k<12;k++){
    int d = lane + 64*k;
    float a = (float)Wh[(size_t)row*EMBD + d];
    d1 += a*Svec[d];
    d2 += a*Pvec[d];
    d3 += a*Tm[(size_t)row*EMBD + d];
    dl += a*(float)Eh[(size_t)lp*EMBD + d];
    dr += a*(float)Eh[(size_t)rp*EMBD + d];
  }
  d1=waveRedSum(d1); d2=waveRedSum(d2); d3=waveRedSum(d3);
  dl=waveRedSum(dl); dr=waveRedSum(dr);
  if(lane==0){
    double c = (double)cvec[row], Q = (double)QQ[0], Q2 = (double)QQ[1], Nn = (double)N_ENT;
    double su  = Nn*c - Q + 2.0*(double)d1;
    double su2 = Nn*c*c - 2.0*c*Q + Q2 + 4.0*(c*(double)d1 - (double)d2) + 4.0*(double)d3;
    double ul = c - (double)qn[lp] + 2.0*(double)dl;
    double ur = c - (double)qn[rp] + 2.0*(double)dr;
    su -= ul + ur;
    if(lp != rp) su2 -= ul*ul + ur*ur;
    double mu = su/Nn;
    double var = su2/Nn - mu*mu;
    double sd = sqrt(fmax(var, 0.0));
    double al = 20.0/sd;
    alpha[row] = (float)al;
    betav[row] = (float)(8.0 - al*mu);
  }
}

__device__ inline void lseMerge(float& mx, float& sm, float om, float os){
  if(om > mx){ sm = sm*expf(mx-om) + os; mx = om; }
  else if(om != -INFINITY){ sm += os*expf(om-mx); }
}

// ---- pass B: 128x128 f16 MFMA (DMA staging + XOR swizzle), two-pass masked-LSE epilogue.
//      Epilogue math: al>0 and (al,be) row-constant across the 16 lanes of a row, so encode
//      the mask into u (u'=0 -> z=be; lp==rp -> u'=-u): max z = al*max(u')+be and
//      sm = sum exp(al*(u'-umax)). NOTE: exp arg MUST be al*(u-umax), never
//      fmaf(al,u,-al*umax) -- fmaf's exact product vs the rounded t gives arg up to
//      +ulp(al*1e30) ~ +2e25 on pad columns -> expf=inf -> inf*0=NaN downstream (r4 failure).
//      u-umax <= 0 is guaranteed by fmaxf, so exp arg <= 0 always.
//      __launch_bounds__(256,3) is the MEASURED register-allocation sweet spot (r5/r7/r8/r9 arc):
//        (256,3): VGPR 64 (+64 AGPR = 128/wave, budget 170) -> 3 blk/CU, 40% occ, 138us.
//        (256,5): budget 102 < 128 footprint -> acc spills to scratch, WRITE 31->760MB, 341us.
//        (256):   no bound -> allocator bloats to 88 VGPR -> ~2 blk/CU, 21.6% occ, 224us.
//      Do not change this clause without re-measuring VGPR_Count + WRITE_SIZE.
//      1D grid 3840, XCD-ownership: id = xcd + 8*m + 128*tt -> ntile = xcd + 8*tt.
__global__ __launch_bounds__(256,3) void k_gemmB(const _Float16* __restrict__ Wh, const _Float16* __restrict__ Eh,
    const float* __restrict__ cvec, const float* __restrict__ qn, const int* __restrict__ tp,
    const float* __restrict__ alpha, const float* __restrict__ betav, float* pm, float* ps){
  __shared__ __align__(16) _Float16 As[128*64];
  __shared__ __align__(16) _Float16 Bs[128*64];
  int id = blockIdx.x;
  int ntile = (id & 7) + ((id >> 7) << 3);
  int m0 = ((id >> 3) & 15) * 128;
  int n0 = ntile * 128;
  int tid = threadIdx.x;
  int w = tid>>6, lane = tid&63;
  int quad = lane>>4, l15 = lane&15;
  int lr = lane>>3, lc = lane&7;
  int wm = (w&1)*64, wn = (w>>1)*64;
  f32x4 acc[4][4];
  #pragma unroll
  for(int i=0;i<4;i++)
    #pragma unroll
    for(int j=0;j<4;j++) acc[i][j] = (f32x4){0.f,0.f,0.f,0.f};
  for(int k0=0;k0<EMBD;k0+=64){
    #pragma unroll
    for(int p=0;p<4;p++){
      int r = p*32 + w*8 + lr;
      int cg = lc ^ (r&7);
      gl_lds16(Wh + (size_t)(m0+r)*EMBD + k0 + cg*8, As + (p*32 + w*8)*64);
      gl_lds16(Eh + (size_t)(n0+r)*EMBD + k0 + cg*8, Bs + (p*32 + w*8)*64);
    }
    __syncthreads();
    #pragma unroll
    for(int ks=0;ks<2;ks++){
      half8 af[4], bf[4];
      #pragma unroll
      for(int i=0;i<4;i++){
        int ml = wm + i*16 + l15;
        af[i] = *(half8*)(As + ml*64 + (((ks<<2)|quad) ^ (ml&7))*8);
      }
      #pragma unroll
      for(int j=0;j<4;j++){
        int nl = wn + j*16 + l15;
        bf[j] = *(half8*)(Bs + nl*64 + (((ks<<2)|quad) ^ (nl&7))*8);
      }
      #pragma unroll
      for(int i=0;i<4;i++)
        #pragma unroll
        for(int j=0;j<4;j++)
          acc[i][j] = __builtin_amdgcn_mfma_f32_16x16x32_f16(af[i], bf[j], acc[i][j], 0,0,0);
    }
    __syncthreads();
  }
  // epilogue: two-pass masked LSE over this wave's 64 cols; fmax/add butterflies over 16 lanes/row.
  float qv[4]; int jv[4];
  #pragma unroll
  for(int j=0;j<4;j++){ jv[j] = n0 + wn + j*16 + l15; qv[j] = qn[jv[j]]; }
  int ptile = ntile*2 + (w>>1);
  #pragma unroll
  for(int i=0;i<4;i++){
    int mbase = m0 + wm + i*16 + quad*4;
    #pragma unroll
    for(int r=0;r<4;r++){
      int mg = mbase + r;
      int pi = mg & (B_PAIR-1);
      int lp = tp[2*pi], rp = tp[2*pi+1];
      float cv = cvec[mg], al = alpha[mg], be = betav[mg];
      float u[4];
      #pragma unroll
      for(int j=0;j<4;j++){
        float uu = fmaf(2.f, acc[i][j][r], cv - qv[j]);
        if(jv[j]==lp || jv[j]==rp) uu = (lp==rp) ? -uu : 0.f;
        u[j] = uu;
      }
      float umax = fmaxf(fmaxf(u[0],u[1]), fmaxf(u[2],u[3]));
      #pragma unroll
      for(int m=8;m>=1;m>>=1) umax = fmaxf(umax, __shfl_xor(umax, m, 64));
      float s = __expf(al*(u[0]-umax)) + __expf(al*(u[1]-umax))
              + __expf(al*(u[2]-umax)) + __expf(al*(u[3]-umax));
      #pragma unroll
      for(int m=8;m>=1;m>>=1) s += __shfl_xor(s, m, 64);
      if(l15==0){ pm[(size_t)mg*PTILES + ptile] = fmaf(al, umax, be); ps[(size_t)mg*PTILES + ptile] = s; }
    }
  }
}

// ---- combine per-tile LSE partials + fused final mean via atomic ticket: block per row ----
__global__ __launch_bounds__(256) void k_lse2(const float* __restrict__ pm, const float* __restrict__ ps,
                        float* accum, int* done, float* out){
  __shared__ float shm[256], shs[256];
  int row = blockIdx.x, tid = threadIdx.x;
  float mx = -INFINITY, sm = 0.f;
  for(int t=tid;t<PTILES;t+=256) lseMerge(mx, sm, pm[(size_t)row*PTILES+t], ps[(size_t)row*PTILES+t]);
  shm[tid]=mx; shs[tid]=sm;
  __syncthreads();
  for(int w=128;w>0;w>>=1){
    if(tid<w){
      float m2=shm[tid], s2=shs[tid];
      lseMerge(m2, s2, shm[tid+w], shs[tid+w]);
      shm[tid]=m2; shs[tid]=s2;
    }
    __syncthreads();
  }
  if(tid==0){
    float l = shm[0] + logf(shs[0]);
    atomicAdd(accum, l);
    __threadfence();
    int t = atomicAdd(done, 1);
    if(t == 2*B_PAIR - 1){
      __threadfence();
      float total = atomicAdd(accum, 0.0f);
      out[0] = total / (float)B_PAIR;
    }
  }
}

extern "C" void kernel_launch(void* const* d_in, const int* in_sizes, int n_in,
                              void* d_out, int out_size, void* d_ws, size_t ws_size,
                              hipStream_t stream) {
  const float* ent_emb = (const float*)d_in[0];
  const float* rel_emb = (const float*)d_in[1];
  const float* attn_e  = (const float*)d_in[2];
  const float* attn_r  = (const float*)d_in[3];
  const int* adj     = (const int*)d_in[5];
  const int* r_index = (const int*)d_in[6];
  const int* ent_adj = (const int*)d_in[7];
  const int* rel_adj = (const int*)d_in[8];
  const int* tp      = (const int*)d_in[9];
  float* out = (float*)d_out;

  const int* adj_row = adj;
  const int* adj_col = adj + T_EDGE;
  const int* rid1    = r_index + T_EDGE;

  char* base = (char*)d_ws;
  size_t off = 0;
  auto A = [&](size_t b)->void*{ void* p = base + off; off = (off + b + 255) & ~(size_t)255; return p; };
  // zero region
  int*   cntA  = (int*)  A((size_t)N_ENT*4);
  int*   cntE  = (int*)  A((size_t)N_ENT*4);
  int*   cntR  = (int*)  A((size_t)N_ENT*4);
  float* G     = (float*)A((size_t)EMBD*EMBD*4);
  float* Svec  = (float*)A(EMBD*4);
  float* Pvec  = (float*)A(EMBD*4);
  float* QQ    = (float*)A(2*4);
  float* accum = (float*)A(4);
  int*   done  = (int*)  A(4);
  size_t zero_end = off;
  // plain buffers
  int* startA = (int*)A((size_t)(N_ENT+1)*4);
  int* startE = (int*)A((size_t)(N_ENT+1)*4);
  int* startR = (int*)A((size_t)(N_ENT+1)*4);
  int* curA   = (int*)A((size_t)N_ENT*4);
  int* curE   = (int*)A((size_t)N_ENT*4);
  int* curR   = (int*)A((size_t)N_ENT*4);
  int* part   = (int*)A(3*SCB*4);
  int* tots   = (int*)A(3*4);
  int* scolA  = (int*)A((size_t)T_EDGE*4);
  int* sridA  = (int*)A((size_t)T_EDGE*4);
  int* scolE  = (int*)A((size_t)NNZ_E*4);
  int* scolR  = (int*)A((size_t)NNZ_E*4);
  _Float16* Eh = (_Float16*)A((size_t)NPAD*EMBD*2);   // pad rows zeroed in k_prep
  // region X: phase-aliased (featC0/featC1 -> embT -> pm/ps)
  char* X = (char*)A((size_t)EMBD*NPAD*2);   // 47.2 MB
  _Float16* featC0 = (_Float16*)X;                       // 15.4 MB
  _Float16* featC1 = (_Float16*)(X + 16u*1024u*1024u);   // 15.4 MB
  _Float16* embT   = (_Float16*)X;
  float*    pm     = (float*)X;                          // 2048*480*4 = 3.93 MB
  float*    ps     = (float*)(X + 8u*1024u*1024u);
  _Float16* relnH  = (_Float16*)A((size_t)R_REL*128*2);
  _Float16* ehE   = (_Float16*)A((size_t)N_ENT*128*2);
  _Float16* ehR   = (_Float16*)A((size_t)R_REL*128*2);
  float* expdot  = (float*)A(4*R_REL*4);
  _Float16* Wh   = (_Float16*)A((size_t)2*B_PAIR*EMBD*2);
  float* Tm      = (float*)A((size_t)2*B_PAIR*EMBD*4);
  float* cvec    = (float*)A(2*B_PAIR*4);
  float* qn      = (float*)A((size_t)NPAD*4);
  float* alpha   = (float*)A(2*B_PAIR*4);
  float* betav   = (float*)A(2*B_PAIR*4);
  (void)ws_size; (void)in_sizes; (void)n_in; (void)out_size;

  hipMemsetAsync(d_ws, 0, zero_end, stream);

  // ---- fused prep: fp16 conversion + Eh pad zero + relnorm/expdot + edge counts ----
  k_prep<<<(N_ENT*128+255)/256, 256, 0, stream>>>(ent_emb, rel_emb, attn_e, attn_r,
                                                  ehE, ehR, Eh, relnH, expdot,
                                                  adj_row, cntA, ent_adj, cntE, rel_adj, cntR);

  // ---- parallel 3-phase scan ----
  dim3 gsa(SCB, 3);
  k_scanA<<<gsa, 256, 0, stream>>>(cntA, cntE, cntR, startA, startE, startR, part);
  k_scanB<<<1, 256, 0, stream>>>(part, tots);
  k_scanC<<<gsa, 256, 0, stream>>>(startA, startE, startR, curA, curE, curR, part, tots);
  k_scatter3<<<(NNZ_E+255)/256, 256, 0, stream>>>(adj_row, adj_col, rid1, curA, scolA, sridA,
                                                  ent_adj, ent_adj+NNZ_E, curE, scolE,
                                                  rel_adj, rel_adj+NNZ_E, curR, scolR);

  // ---- fused dual GAT stack: avg (ent|rel merged) -> layer0 -> layer1 ----
  dim3 gavg(N_ENT/4, 2);
  k_avg2<<<gavg, 256, 0, stream>>>(startE, scolE, ehE, startR, scolR, ehR, featC0, Eh);
  k_edge2<<<N_ENT/4, 256, 0, stream>>>(startA, scolA, sridA, relnH, expdot + 0*R_REL, expdot + 2*R_REL,
                                       featC0, featC1, Eh, 128, 512);
  k_edge2<<<N_ENT/4, 256, 0, stream>>>(startA, scolA, sridA, relnH, expdot + 1*R_REL, expdot + 3*R_REL,
                                       featC1, featC0, Eh, 256, 640);

  // ---- fused post pass: transp | gather | qnstats ----
  k_post<<<5760 + B_PAIR + 240, 256, 0, stream>>>(Eh, embT, tp, Wh, cvec, qn, Svec, Pvec, QQ);

  // ---- align loss ----
  k_syrk<<<1152, 256, 0, stream>>>(embT, G);
  dim3 gT(EMBD/64, 32);
  k_gemmTh<<<gT, 64, 0, stream>>>(Wh, G, Tm);
  k_rowstats<<<2*B_PAIR/4, 256, 0, stream>>>(Wh, Tm, Eh, qn, cvec, tp, Svec, Pvec, QQ, alpha, betav);
  k_gemmB<<<NT128*16, 256, 0, stream>>>(Wh, Eh, cvec, qn, tp, alpha, betav, pm, ps);
  k_lse2<<<2*B_PAIR, 256, 0, stream>>>(pm, ps, accum, done, out);
}